// Round 3
// baseline (353.170 us; speedup 1.0000x reference)
//
#include <hip/hip_runtime.h>

typedef __attribute__((ext_vector_type(4))) float v4f;
typedef __attribute__((ext_vector_type(8))) short v8s;
typedef __attribute__((ext_vector_type(4))) unsigned v4u;

// full RNE fp32->bf16 (prep kernel only)
__device__ __forceinline__ short f2bf(float f) {
  union { float f; unsigned u; } v; v.f = f;
  unsigned r = v.u + 0x7FFFu + ((v.u >> 16) & 1u);
  return (short)(r >> 16);
}
// round-half-up pack of 2 floats -> bf16x2 (hot paths; statistically same error)
__device__ __forceinline__ unsigned pk_fast(float a, float b) {
  union { float f; unsigned u; } x, y; x.f = a; y.f = b;
  return ((x.u + 0x8000u) >> 16) | ((y.u + 0x8000u) & 0xFFFF0000u);
}

// Pack W1 [128x256] and W2 [256x256] (row-major [k][n], fp32) into bf16 MFMA
// A-operand fragment order for the transposed product (W^T as A):
//   lane l of fragment (mt, kt) holds A'[n = mt*16 + (l&15)][k = kt*32 + (l>>4)*8 + j]
__global__ void pack_weights(const float* __restrict__ W1, const float* __restrict__ W2,
                             short* __restrict__ pW1, short* __restrict__ pW2) {
  int tid = blockIdx.x * 256 + threadIdx.x;
  if (tid < 32768) {
    int j = tid & 7, l = (tid >> 3) & 63, frag = tid >> 9;
    int mt = frag >> 2, kt = frag & 3;
    int n = mt * 16 + (l & 15);
    int k = kt * 32 + ((l >> 4) * 8) + j;
    pW1[tid] = f2bf(W1[k * 256 + n]);
  } else if (tid < 98304) {
    int t2 = tid - 32768;
    int j = t2 & 7, l = (t2 >> 3) & 63, frag = t2 >> 9;
    int mt = frag >> 3, kt = frag & 7;
    int n = mt * 16 + (l & 15);
    int k = kt * 32 + ((l >> 4) * 8) + j;
    pW2[t2] = f2bf(W2[k * 256 + n]);
  }
}

#define LDX_S 136   // 128 + 8 pad (row = 272 B, 16B-aligned, 2-way banks max per phase)
#define LDH_S 264   // 256 + 8 pad

// Persistent fused 3-layer MLP. 256 threads = 4 waves; wave w owns hidden rows
// [w*64, w*64+64). All W1/W2 fragments live in registers for the whole kernel;
// each block grid-strides over 64-edge tiles, prefetching the next tile's
// gather into registers one iteration ahead.
__global__ __launch_bounds__(256, 1) void mlp_persist(
    const float* __restrict__ xu, const float* __restrict__ xm,
    const void* __restrict__ eidx,
    const short* __restrict__ pW1, const short* __restrict__ pW2,
    const float* __restrict__ b1, const float* __restrict__ b2,
    const float* __restrict__ W3, const float* __restrict__ b3,
    float* __restrict__ out, int E)
{
  __shared__ __align__(16) short ldsX[64 * LDX_S];   // [edge][k0..127] bf16
  __shared__ __align__(16) short ldsH[64 * LDH_S];   // [edge][h0..255] bf16
  __shared__ __align__(16) float ldsPart[64 * 16];   // [edge][wave*4+quad]

  const int t    = threadIdx.x;
  const int w    = t >> 6;
  const int lane = t & 63;
  const int quad = lane >> 4;
  const int lp   = lane & 15;

  // ---- resident weight fragments (loaded once)
  const v8s* w1v = (const v8s*)pW1;
  const v8s* w2v = (const v8s*)pW2;
  v8s rW1[4][4], rW2[4][8];
#pragma unroll
  for (int mi = 0; mi < 4; ++mi)
#pragma unroll
    for (int kt = 0; kt < 4; ++kt)
      rW1[mi][kt] = w1v[(((w * 4 + mi) * 4) + kt) * 64 + lane];
#pragma unroll
  for (int mi = 0; mi < 4; ++mi)
#pragma unroll
    for (int kt = 0; kt < 8; ++kt)
      rW2[mi][kt] = w2v[(((w * 4 + mi) * 8) + kt) * 64 + lane];

  // ---- resident bias / W3 fragments
  v4f rb1[4], rb2[4], rw3[4];
#pragma unroll
  for (int mi = 0; mi < 4; ++mi) {
    int nh0 = w * 64 + mi * 16 + quad * 4;
    rb1[mi] = *(const v4f*)(b1 + nh0);
    rb2[mi] = *(const v4f*)(b2 + nh0);
    rw3[mi] = *(const v4f*)(W3 + nh0);
  }
  const float bias3 = b3[0];

  // ---- index dtype detection (wave-uniform): int64 iff odd 32-bit words are 0
  const unsigned* ew = (const unsigned*)eidx;
  unsigned oddw = (lane < 32) ? ew[2 * lane + 1] : 0u;
  const bool i64 = (__ballot(oddw != 0u) == 0ull);

  const int gi = t >> 2, gq = t & 3;   // gather role: 4 threads/edge, 16 floats each
  const int ntiles = (E + 63) >> 6;

  v4f U[4], M[4];
  auto prefetch = [&](int tl) {
    int gE = tl * 64 + gi;
    if (gE >= E) gE = 0;
    int row, col;
    if (i64) {
      const long long* p = (const long long*)eidx;
      row = (int)p[gE]; col = (int)p[(long long)E + gE];
    } else {
      const int* p = (const int*)eidx;
      row = p[gE]; col = p[E + gE];
    }
    const v4f* pu = (const v4f*)(xu + (size_t)row * 64 + gq * 16);
    const v4f* pm = (const v4f*)(xm + (size_t)col * 64 + gq * 16);
#pragma unroll
    for (int s = 0; s < 4; ++s) { U[s] = pu[s]; M[s] = pm[s]; }
  };

  int tile = blockIdx.x;
  if (tile < ntiles) prefetch(tile);

  for (; tile < ntiles; tile += gridDim.x) {
    // ---- commit prefetched gather -> ldsX (convert to bf16)
    {
      short* px = &ldsX[gi * LDX_S + gq * 16];
      v4u a0 = { pk_fast(U[0][0], U[0][1]), pk_fast(U[0][2], U[0][3]),
                 pk_fast(U[1][0], U[1][1]), pk_fast(U[1][2], U[1][3]) };
      v4u a1 = { pk_fast(U[2][0], U[2][1]), pk_fast(U[2][2], U[2][3]),
                 pk_fast(U[3][0], U[3][1]), pk_fast(U[3][2], U[3][3]) };
      v4u c0 = { pk_fast(M[0][0], M[0][1]), pk_fast(M[0][2], M[0][3]),
                 pk_fast(M[1][0], M[1][1]), pk_fast(M[1][2], M[1][3]) };
      v4u c1 = { pk_fast(M[2][0], M[2][1]), pk_fast(M[2][2], M[2][3]),
                 pk_fast(M[3][0], M[3][1]), pk_fast(M[3][2], M[3][3]) };
      *(v4u*)(px)      = a0; *(v4u*)(px + 8)  = a1;   // user  -> k 0..63
      *(v4u*)(px + 64) = c0; *(v4u*)(px + 72) = c1;   // movie -> k 64..127
    }
    __syncthreads();                                  // B1: X visible

    // ---- issue next tile's gather now; whole tile body hides its latency
    prefetch(tile + gridDim.x);

    // ---- layer 1: K=128, weights from registers
    v4f acc[4][4] = {};
#pragma unroll
    for (int kt = 0; kt < 4; ++kt) {
      v8s b[4];
#pragma unroll
      for (int ni = 0; ni < 4; ++ni)
        b[ni] = *(const v8s*)&ldsX[(ni * 16 + lp) * LDX_S + kt * 32 + quad * 8];
#pragma unroll
      for (int mi = 0; mi < 4; ++mi)
#pragma unroll
        for (int ni = 0; ni < 4; ++ni)
          acc[mi][ni] = __builtin_amdgcn_mfma_f32_16x16x32_bf16(rW1[mi][kt], b[ni], acc[mi][ni], 0, 0, 0);
    }

    // ---- epilogue 1: bias + relu + bf16 -> ldsH[e][n]
#pragma unroll
    for (int mi = 0; mi < 4; ++mi) {
      int nh0 = w * 64 + mi * 16 + quad * 4;
#pragma unroll
      for (int ni = 0; ni < 4; ++ni) {
        int e = ni * 16 + lp;
        v4f v = acc[mi][ni] + rb1[mi];
        float x0 = v[0] > 0.f ? v[0] : 0.f;
        float x1 = v[1] > 0.f ? v[1] : 0.f;
        float x2 = v[2] > 0.f ? v[2] : 0.f;
        float x3 = v[3] > 0.f ? v[3] : 0.f;
        unsigned p0 = pk_fast(x0, x1), p1 = pk_fast(x2, x3);
        *(unsigned*)&ldsH[e * LDH_S + nh0]     = p0;
        *(unsigned*)&ldsH[e * LDH_S + nh0 + 2] = p1;
      }
    }
    __syncthreads();                                  // B2: H visible

    // ---- layer 2: K=256, weights from registers
    v4f acc2[4][4] = {};
#pragma unroll
    for (int kt = 0; kt < 8; ++kt) {
      v8s b[4];
#pragma unroll
      for (int ni = 0; ni < 4; ++ni)
        b[ni] = *(const v8s*)&ldsH[(ni * 16 + lp) * LDH_S + kt * 32 + quad * 8];
#pragma unroll
      for (int mi = 0; mi < 4; ++mi)
#pragma unroll
        for (int ni = 0; ni < 4; ++ni)
          acc2[mi][ni] = __builtin_amdgcn_mfma_f32_16x16x32_bf16(rW2[mi][kt], b[ni], acc2[mi][ni], 0, 0, 0);
    }

    // ---- layer 3 (fp32 VALU): partial dot with W3
    float s[4] = {0.f, 0.f, 0.f, 0.f};
#pragma unroll
    for (int mi = 0; mi < 4; ++mi) {
#pragma unroll
      for (int ni = 0; ni < 4; ++ni) {
        v4f v = acc2[mi][ni] + rb2[mi];
#pragma unroll
        for (int r = 0; r < 4; ++r) {
          float x = v[r] > 0.f ? v[r] : 0.f;
          s[ni] += x * rw3[mi][r];
        }
      }
    }
#pragma unroll
    for (int ni = 0; ni < 4; ++ni)
      ldsPart[(ni * 16 + lp) * 16 + w * 4 + quad] = s[ni];
    __syncthreads();                                  // B3: partials visible

    if (t < 64) {
      const v4f* pp = (const v4f*)&ldsPart[t * 16];
      v4f p0 = pp[0], p1 = pp[1], p2 = pp[2], p3 = pp[3];
      float r = bias3
              + (p0[0] + p0[1] + p0[2] + p0[3]) + (p1[0] + p1[1] + p1[2] + p1[3])
              + (p2[0] + p2[1] + p2[2] + p2[3]) + (p3[0] + p3[1] + p3[2] + p3[3]);
      int o = tile * 64 + t;
      if (o < E) out[o] = r;
    }
  }
}

extern "C" void kernel_launch(void* const* d_in, const int* in_sizes, int n_in,
                              void* d_out, int out_size, void* d_ws, size_t ws_size,
                              hipStream_t stream) {
  const float* xu  = (const float*)d_in[0];
  const float* xm  = (const float*)d_in[1];
  const void*  ei  = d_in[2];
  const float* W1  = (const float*)d_in[3];
  const float* b1  = (const float*)d_in[4];
  const float* W2  = (const float*)d_in[5];
  const float* b2  = (const float*)d_in[6];
  const float* W3  = (const float*)d_in[7];
  const float* b3  = (const float*)d_in[8];
  float* out = (float*)d_out;

  const int E = in_sizes[2] / 2;

  short* pW1 = (short*)d_ws;          // 64 KB
  short* pW2 = pW1 + 32768;           // 128 KB

  hipLaunchKernelGGL(pack_weights, dim3(384), dim3(256), 0, stream, W1, W2, pW1, pW2);

  const int ntiles = (E + 63) / 64;
  const int nblk = ntiles < 256 ? ntiles : 256;
  hipLaunchKernelGGL(mlp_persist, dim3(nblk), dim3(256), 0, stream,
                     xu, xm, ei, pW1, pW2, b1, b2, W3, b3, out, E);
}

// Round 4
// 269.419 us; speedup vs baseline: 1.3109x; 1.3109x over previous
//
#include <hip/hip_runtime.h>

typedef __attribute__((ext_vector_type(4))) float v4f;
typedef __attribute__((ext_vector_type(8))) short v8s;
typedef __attribute__((ext_vector_type(4))) unsigned v4u;
typedef __attribute__((ext_vector_type(2))) unsigned v2u;

// full RNE fp32->bf16 (prep kernel only)
__device__ __forceinline__ short f2bf(float f) {
  union { float f; unsigned u; } v; v.f = f;
  unsigned r = v.u + 0x7FFFu + ((v.u >> 16) & 1u);
  return (short)(r >> 16);
}
// round-half-up pack of 2 floats -> bf16x2 (hot paths)
__device__ __forceinline__ unsigned pk_fast(float a, float b) {
  union { float f; unsigned u; } x, y; x.f = a; y.f = b;
  return ((x.u + 0x8000u) >> 16) | ((y.u + 0x8000u) & 0xFFFF0000u);
}

// Pack W1 [128x256] and W2 [256x256] (row-major [k][n], fp32) into bf16 MFMA
// A-operand fragment order for the transposed product (W^T as A):
//   lane l of fragment (mt, kt) holds A'[n = mt*16 + (l&15)][k = kt*32 + (l>>4)*8 + j]
__global__ void pack_weights(const float* __restrict__ W1, const float* __restrict__ W2,
                             short* __restrict__ pW1, short* __restrict__ pW2) {
  int tid = blockIdx.x * 256 + threadIdx.x;
  if (tid < 32768) {
    int j = tid & 7, l = (tid >> 3) & 63, frag = tid >> 9;
    int mt = frag >> 2, kt = frag & 3;
    int n = mt * 16 + (l & 15);
    int k = kt * 32 + ((l >> 4) * 8) + j;
    pW1[tid] = f2bf(W1[k * 256 + n]);
  } else if (tid < 98304) {
    int t2 = tid - 32768;
    int j = t2 & 7, l = (t2 >> 3) & 63, frag = t2 >> 9;
    int mt = frag >> 3, kt = frag & 7;
    int n = mt * 16 + (l & 15);
    int k = kt * 32 + ((l >> 4) * 8) + j;
    pW2[t2] = f2bf(W2[k * 256 + n]);
  }
}

#define LDX_S 136   // 128 + 8 pad shorts
#define LDH_S 264   // 256 + 8 pad shorts
#define LDP_S 36    // 32 + 4 pad floats

// Persistent fused 3-layer MLP. 512 threads = 8 waves; wave w owns hidden rows
// [w*32, w*32+32): weight slice = 8+16 v8s = 96 VGPRs (fits 2 waves/SIMD, no
// spill — R3's 4-wave/192-reg split spilled). 256 blocks grid-stride tiles of
// 64 edges; indices prefetched 2 tiles ahead, features 1 tile ahead.
__global__ __launch_bounds__(512, 2) void mlp_p8(
    const float* __restrict__ xu, const float* __restrict__ xm,
    const void* __restrict__ eidx,
    const short* __restrict__ pW1, const short* __restrict__ pW2,
    const float* __restrict__ b1, const float* __restrict__ b2,
    const float* __restrict__ W3, const float* __restrict__ b3,
    float* __restrict__ out, int E)
{
  __shared__ __align__(16) short ldsX[64 * LDX_S];   // [edge][k0..127] bf16
  __shared__ __align__(16) short ldsH[64 * LDH_S];   // [edge][h0..255] bf16
  __shared__ __align__(16) float ldsPart[64 * LDP_S];// [edge][slot0..31]

  const int t    = threadIdx.x;
  const int w    = t >> 6;        // wave 0..7 : hidden slice w*32
  const int lane = t & 63;
  const int quad = lane >> 4;
  const int lp   = lane & 15;

  // ---- resident weight fragments (96 VGPRs/wave, loaded once)
  const v8s* w1v = (const v8s*)pW1;
  const v8s* w2v = (const v8s*)pW2;
  v8s rW1[2][4], rW2[2][8];
#pragma unroll
  for (int mi = 0; mi < 2; ++mi)
#pragma unroll
    for (int kt = 0; kt < 4; ++kt)
      rW1[mi][kt] = w1v[(((w * 2 + mi) * 4) + kt) * 64 + lane];
#pragma unroll
  for (int mi = 0; mi < 2; ++mi)
#pragma unroll
    for (int kt = 0; kt < 8; ++kt)
      rW2[mi][kt] = w2v[(((w * 2 + mi) * 8) + kt) * 64 + lane];

  // ---- resident bias / W3 fragments
  v4f rb1[2], rb2[2], rw3[2];
#pragma unroll
  for (int mi = 0; mi < 2; ++mi) {
    int nh0 = w * 32 + mi * 16 + quad * 4;
    rb1[mi] = *(const v4f*)(b1 + nh0);
    rb2[mi] = *(const v4f*)(b2 + nh0);
    rw3[mi] = *(const v4f*)(W3 + nh0);
  }
  const float bias3 = b3[0];

  // ---- index dtype detection: int64 iff odd 32-bit words are all zero
  const unsigned* ew = (const unsigned*)eidx;
  unsigned oddw = (lane < 32) ? ew[2 * lane + 1] : 0u;
  const bool i64 = (__ballot(oddw != 0u) == 0ull);

  const int gi = t >> 3, gq = t & 7;   // gather: 8 threads/edge, 8 feats each side
  const int ntiles = (E + 63) >> 6;

  auto loadIdx = [&](int tl, int& row, int& col) {
    int gE = tl * 64 + gi;
    if (gE >= E || gE < 0) gE = 0;
    if (i64) {
      const long long* p = (const long long*)eidx;
      row = (int)p[gE]; col = (int)p[(long long)E + gE];
    } else {
      const int* p = (const int*)eidx;
      row = p[gE]; col = p[E + gE];
    }
  };

  v4f U0, U1, M0, M1;
  auto issueUM = [&](int row, int col) {
    const v4f* pu = (const v4f*)(xu + (size_t)row * 64 + gq * 8);
    const v4f* pm = (const v4f*)(xm + (size_t)col * 64 + gq * 8);
    U0 = pu[0]; U1 = pu[1]; M0 = pm[0]; M1 = pm[1];
  };

  // prologue: idx(t0) -> feats(t0) -> idx(t0+stride)
  int rowN, colN;
  loadIdx(blockIdx.x, rowN, colN);
  issueUM(rowN, colN);
  loadIdx(blockIdx.x + gridDim.x, rowN, colN);

  for (int tile = blockIdx.x; tile < ntiles; tile += gridDim.x) {
    // ---- commit prefetched gather -> ldsX (bf16)
    {
      short* px = &ldsX[gi * LDX_S + gq * 8];
      v4u a = { pk_fast(U0[0], U0[1]), pk_fast(U0[2], U0[3]),
                pk_fast(U1[0], U1[1]), pk_fast(U1[2], U1[3]) };
      v4u c = { pk_fast(M0[0], M0[1]), pk_fast(M0[2], M0[3]),
                pk_fast(M1[0], M1[1]), pk_fast(M1[2], M1[3]) };
      *(v4u*)(px)      = a;     // user  -> k 0..63
      *(v4u*)(px + 64) = c;     // movie -> k 64..127
    }
    __syncthreads();                                  // B1: X visible

    // ---- pipeline: features for tile+stride, indices for tile+2*stride
    issueUM(rowN, colN);
    loadIdx(tile + 2 * gridDim.x, rowN, colN);

    // ---- layer 1: K=128, weights resident
    v4f acc[2][4] = {};
#pragma unroll
    for (int kt = 0; kt < 4; ++kt) {
      v8s b[4];
#pragma unroll
      for (int ni = 0; ni < 4; ++ni)
        b[ni] = *(const v8s*)&ldsX[(ni * 16 + lp) * LDX_S + kt * 32 + quad * 8];
#pragma unroll
      for (int mi = 0; mi < 2; ++mi)
#pragma unroll
        for (int ni = 0; ni < 4; ++ni)
          acc[mi][ni] = __builtin_amdgcn_mfma_f32_16x16x32_bf16(rW1[mi][kt], b[ni], acc[mi][ni], 0, 0, 0);
    }

    // ---- epilogue 1: bias + relu + bf16 -> ldsH[e][n]
#pragma unroll
    for (int mi = 0; mi < 2; ++mi) {
      int nh0 = w * 32 + mi * 16 + quad * 4;
#pragma unroll
      for (int ni = 0; ni < 4; ++ni) {
        int e = ni * 16 + lp;
        v4f v = acc[mi][ni] + rb1[mi];
        float x0 = v[0] > 0.f ? v[0] : 0.f;
        float x1 = v[1] > 0.f ? v[1] : 0.f;
        float x2 = v[2] > 0.f ? v[2] : 0.f;
        float x3 = v[3] > 0.f ? v[3] : 0.f;
        v2u pw; pw.x = pk_fast(x0, x1); pw.y = pk_fast(x2, x3);
        *(v2u*)&ldsH[e * LDH_S + nh0] = pw;           // ds_write_b64
      }
    }
    __syncthreads();                                  // B2: H visible

    // ---- layer 2: K=256, weights resident
    v4f acc2[2][4] = {};
#pragma unroll
    for (int kt = 0; kt < 8; ++kt) {
      v8s b[4];
#pragma unroll
      for (int ni = 0; ni < 4; ++ni)
        b[ni] = *(const v8s*)&ldsH[(ni * 16 + lp) * LDH_S + kt * 32 + quad * 8];
#pragma unroll
      for (int mi = 0; mi < 2; ++mi)
#pragma unroll
        for (int ni = 0; ni < 4; ++ni)
          acc2[mi][ni] = __builtin_amdgcn_mfma_f32_16x16x32_bf16(rW2[mi][kt], b[ni], acc2[mi][ni], 0, 0, 0);
    }

    // ---- layer 3 (fp32 VALU): partial dot with W3 over this wave's 32 h
    float s[4] = {0.f, 0.f, 0.f, 0.f};
#pragma unroll
    for (int mi = 0; mi < 2; ++mi) {
#pragma unroll
      for (int ni = 0; ni < 4; ++ni) {
        v4f v = acc2[mi][ni] + rb2[mi];
#pragma unroll
        for (int r = 0; r < 4; ++r) {
          float x = v[r] > 0.f ? v[r] : 0.f;
          s[ni] += x * rw3[mi][r];
        }
      }
    }
#pragma unroll
    for (int ni = 0; ni < 4; ++ni)
      ldsPart[(ni * 16 + lp) * LDP_S + w * 4 + quad] = s[ni];  // <=4-way banks
    __syncthreads();                                  // B3: partials visible

    // ---- final reduce: 32 partials per edge, contiguous v4f reads
    if (t < 64) {
      const v4f* pp = (const v4f*)&ldsPart[t * LDP_S];
      float r = bias3;
#pragma unroll
      for (int c = 0; c < 8; ++c) {
        v4f p = pp[c];
        r += (p[0] + p[1]) + (p[2] + p[3]);
      }
      int o = tile * 64 + t;
      if (o < E) out[o] = r;
    }
  }
}

extern "C" void kernel_launch(void* const* d_in, const int* in_sizes, int n_in,
                              void* d_out, int out_size, void* d_ws, size_t ws_size,
                              hipStream_t stream) {
  const float* xu  = (const float*)d_in[0];
  const float* xm  = (const float*)d_in[1];
  const void*  ei  = d_in[2];
  const float* W1  = (const float*)d_in[3];
  const float* b1  = (const float*)d_in[4];
  const float* W2  = (const float*)d_in[5];
  const float* b2  = (const float*)d_in[6];
  const float* W3  = (const float*)d_in[7];
  const float* b3  = (const float*)d_in[8];
  float* out = (float*)d_out;

  const int E = in_sizes[2] / 2;

  short* pW1 = (short*)d_ws;          // 64 KB
  short* pW2 = pW1 + 32768;           // 128 KB

  hipLaunchKernelGGL(pack_weights, dim3(384), dim3(256), 0, stream, W1, W2, pW1, pW2);

  const int ntiles = (E + 63) / 64;
  const int nblk = ntiles < 256 ? ntiles : 256;
  hipLaunchKernelGGL(mlp_p8, dim3(nblk), dim3(512), 0, stream,
                     xu, xm, ei, pW1, pW2, b1, b2, W3, b3, out, E);
}